// Round 3
// baseline (3145.009 us; speedup 1.0000x reference)
//
#include <hip/hip_runtime.h>
#include <stdint.h>

#define NNODES 100000
#define NEDGES 600000
#define NGRAPH 256
#define KCH 5
#define F1 16
#define O1 64
#define F2 128
#define O2 256
#define FT1 (KCH * F1) /* 80  */
#define FT2 (KCH * F2) /* 640 */

typedef unsigned short ushort_t;

__device__ __forceinline__ float bflo(unsigned int u) {
    union { unsigned int u; float f; } v; v.u = u << 16; return v.f;
}
__device__ __forceinline__ float bfhi(unsigned int u) {
    union { unsigned int u; float f; } v; v.u = u & 0xFFFF0000u; return v.f;
}
__device__ __forceinline__ unsigned int f2bf(float f) {
    union { float f; unsigned int u; } v; v.f = f;
    return (v.u + 0x7FFFu + ((v.u >> 16) & 1u)) >> 16;  // RNE
}
__device__ __forceinline__ unsigned int pack2(float lo, float hi) {
    return (f2bf(hi) << 16) | f2bf(lo);
}

// -------------------- CSR build --------------------

__global__ void k_count(const int* __restrict__ src, const int* __restrict__ dst,
                        int* __restrict__ cntDst, int* __restrict__ cntSrc, int E) {
    int e = blockIdx.x * 256 + threadIdx.x;
    if (e < E) {
        atomicAdd(&cntDst[dst[e]], 1);
        atomicAdd(&cntSrc[src[e]], 1);
    }
}

__global__ void k_dinv(const int* __restrict__ cntDst, const int* __restrict__ cntSrc,
                       float* __restrict__ dinvF, float* __restrict__ dinvR, int n) {
    int i = blockIdx.x * 256 + threadIdx.x;
    if (i < n) {
        int cs = cntSrc[i], cd = cntDst[i];
        dinvF[i] = cs > 0 ? rsqrtf((float)cs) : 0.f;  // deg over src -> fwd norm
        dinvR[i] = cd > 0 ? rsqrtf((float)cd) : 0.f;  // deg over dst -> rev norm
    }
}

// exclusive scan, 512 elems/block
__global__ void k_scan1(const int* __restrict__ in, int* __restrict__ out,
                        int* __restrict__ blksum, int n) {
    __shared__ int a[512];
    __shared__ int s[256];
    int t = threadIdx.x;
    int base = blockIdx.x * 512;
    a[t]       = (base + t < n)       ? in[base + t]       : 0;
    a[t + 256] = (base + t + 256 < n) ? in[base + t + 256] : 0;
    __syncthreads();
    s[t] = a[2 * t] + a[2 * t + 1];
    __syncthreads();
    for (int off = 1; off < 256; off <<= 1) {
        int v = (t >= off) ? s[t - off] : 0;
        __syncthreads();
        s[t] += v;
        __syncthreads();
    }
    int ep = (t > 0) ? s[t - 1] : 0;  // exclusive over pairs
    if (base + 2 * t < n)     out[base + 2 * t]     = ep;
    if (base + 2 * t + 1 < n) out[base + 2 * t + 1] = ep + a[2 * t];
    if (t == 255) blksum[blockIdx.x] = s[255];
}

__global__ void k_scan2(int* __restrict__ blksum, int nb) {
    __shared__ int s[256];
    int t = threadIdx.x;
    s[t] = (t < nb) ? blksum[t] : 0;
    __syncthreads();
    for (int off = 1; off < 256; off <<= 1) {
        int v = (t >= off) ? s[t - off] : 0;
        __syncthreads();
        s[t] += v;
        __syncthreads();
    }
    if (t < nb) blksum[t] = (t > 0) ? s[t - 1] : 0;
}

__global__ void k_scan3(int* __restrict__ out, const int* __restrict__ blksum, int n) {
    int i = blockIdx.x * 512 + threadIdx.x;
    int add = blksum[blockIdx.x];
    if (i < n) out[i] += add;
    if (i + 256 < n) out[i + 256] += add;
}

__global__ void k_tail(int* __restrict__ off_f, int* __restrict__ off_r, int n, int E) {
    if (threadIdx.x == 0) { off_f[n] = E; off_r[n] = E; }
}

__global__ void k_scatter(const int* __restrict__ src, const int* __restrict__ dst,
                          const float* __restrict__ dinvF, const float* __restrict__ dinvR,
                          int* __restrict__ curF, int* __restrict__ curR,
                          int* __restrict__ nbrF, float* __restrict__ wF,
                          int* __restrict__ nbrR, float* __restrict__ wR, int E) {
    int e = blockIdx.x * 256 + threadIdx.x;
    if (e < E) {
        int s = src[e], d = dst[e];
        int p = atomicAdd(&curF[d], 1);
        nbrF[p] = s;
        wF[p] = -dinvF[s] * dinvF[d];
        int q = atomicAdd(&curR[s], 1);
        nbrR[q] = d;
        wR[q] = -dinvR[s] * dinvR[d];
    }
}

__global__ void k_gstart(const int* __restrict__ batch, int* __restrict__ gstart, int n) {
    int g = blockIdx.x * 64 + threadIdx.x;
    if (g > NGRAPH) return;
    if (g == NGRAPH) { gstart[g] = n; return; }
    int lo = 0, hi = n;
    while (lo < hi) {
        int mid = (lo + hi) >> 1;
        if (batch[mid] < g) lo = mid + 1; else hi = mid;
    }
    gstart[g] = lo;
}

// -------------------- compute --------------------

__global__ void k_copyx(const float* __restrict__ x, float* __restrict__ Tx, int n) {
    int tid = blockIdx.x * 256 + threadIdx.x;
    int r = tid >> 2, c = tid & 3;
    if (r < n)
        *(float4*)(Tx + (size_t)r * FT1 + c * 4) =
            *(const float4*)(x + (size_t)r * 16 + c * 4);
}

// fp32 SpMM (layer 1, F=16): Hout[r] = 2*sum - Tx0[r]  (or sum when Tx0==null)
__global__ void k_spmm_f32(const float* __restrict__ Hin, float* __restrict__ Hout,
                           const float* __restrict__ Tx0,
                           const int* __restrict__ off, const int* __restrict__ nbr,
                           const float* __restrict__ wts, int n) {
    int tid = blockIdx.x * 256 + threadIdx.x;
    int r = tid >> 2, c = tid & 3;
    if (r >= n) return;
    int j0 = off[r], j1 = off[r + 1];
    float4 s = {0.f, 0.f, 0.f, 0.f};
    for (int j = j0; j < j1; ++j) {
        int nb = nbr[j];
        float w2 = wts[j];
        const float4 h = *(const float4*)(Hin + (size_t)nb * FT1 + c * 4);
        s.x += w2 * h.x; s.y += w2 * h.y; s.z += w2 * h.z; s.w += w2 * h.w;
    }
    float4 o;
    if (Tx0) {
        const float4 t0 = *(const float4*)(Tx0 + (size_t)r * FT1 + c * 4);
        o.x = 2.f * s.x - t0.x; o.y = 2.f * s.y - t0.y;
        o.z = 2.f * s.z - t0.z; o.w = 2.f * s.w - t0.w;
    } else {
        o = s;
    }
    *(float4*)(Hout + (size_t)r * FT1 + c * 4) = o;
}

// bf16 SpMM (layer 2, F=128): 16 lanes/row, 8 feats/lane (uint4 = 8 bf16)
__global__ void k_spmm_bf(const ushort_t* __restrict__ Hin, ushort_t* __restrict__ Hout,
                          const ushort_t* __restrict__ Tx0,
                          const int* __restrict__ off, const int* __restrict__ nbr,
                          const float* __restrict__ wts, int n) {
    int tid = blockIdx.x * 256 + threadIdx.x;
    int r = tid >> 4, c = tid & 15;
    if (r >= n) return;
    int j0 = off[r], j1 = off[r + 1];
    float s0 = 0.f, s1 = 0.f, s2 = 0.f, s3 = 0.f;
    float s4 = 0.f, s5 = 0.f, s6 = 0.f, s7 = 0.f;
    for (int j = j0; j < j1; ++j) {
        int nb = nbr[j];
        float w2 = wts[j];
        const uint4 hv = *(const uint4*)(Hin + (size_t)nb * FT2 + c * 8);
        s0 = fmaf(bflo(hv.x), w2, s0); s1 = fmaf(bfhi(hv.x), w2, s1);
        s2 = fmaf(bflo(hv.y), w2, s2); s3 = fmaf(bfhi(hv.y), w2, s3);
        s4 = fmaf(bflo(hv.z), w2, s4); s5 = fmaf(bfhi(hv.z), w2, s5);
        s6 = fmaf(bflo(hv.w), w2, s6); s7 = fmaf(bfhi(hv.w), w2, s7);
    }
    if (Tx0) {
        const uint4 t0 = *(const uint4*)(Tx0 + (size_t)r * FT2 + c * 8);
        s0 = 2.f * s0 - bflo(t0.x); s1 = 2.f * s1 - bfhi(t0.x);
        s2 = 2.f * s2 - bflo(t0.y); s3 = 2.f * s3 - bfhi(t0.y);
        s4 = 2.f * s4 - bflo(t0.z); s5 = 2.f * s5 - bfhi(t0.z);
        s6 = 2.f * s6 - bflo(t0.w); s7 = 2.f * s7 - bfhi(t0.w);
    }
    uint4 o;
    o.x = pack2(s0, s1); o.y = pack2(s2, s3);
    o.z = pack2(s4, s5); o.w = pack2(s6, s7);
    *(uint4*)(Hout + (size_t)r * FT2 + c * 8) = o;
}

// layer-1 GEMM: A fp32 [n,80] x W [80,64] -> bf16 out slice (ld=640), bias+relu
__global__ __launch_bounds__(256) void k_gemm1(
    const float* __restrict__ A, const float* __restrict__ W,
    const float* __restrict__ bias, ushort_t* __restrict__ out, int n) {
    constexpr int R = 32;
    int col = threadIdx.x & 63;
    int rg = threadIdx.x >> 6;               // wave index (wave-uniform)
    int row0 = blockIdx.x * 128 + rg * R;
    row0 = __builtin_amdgcn_readfirstlane(row0);
    if (row0 > n - R) row0 = n - R;          // clamp reads in-bounds (benign dup writes)

    float acc[R];
#pragma unroll
    for (int r = 0; r < R; ++r) acc[r] = 0.f;

    const float* Ab = A + (size_t)row0 * FT1;
    for (int f0 = 0; f0 < FT1; f0 += 8) {
        float wv[8];
#pragma unroll
        for (int j = 0; j < 8; ++j) wv[j] = W[(f0 + j) * O1 + col];
#pragma unroll
        for (int r = 0; r < R; ++r) {
            const float* ar = Ab + (size_t)r * FT1 + f0;
#pragma unroll
            for (int j = 0; j < 8; ++j) acc[r] = fmaf(ar[j], wv[j], acc[r]);
        }
    }
    float b = bias[col];
#pragma unroll
    for (int r = 0; r < R; ++r) {
        int row = row0 + r;
        out[(size_t)row * FT2 + col] = (ushort_t)f2bf(fmaxf(acc[r] + b, 0.f));
    }
}

// layer-2 GEMM: A bf16 [n,640] x W [640,256] -> bias+relu -> pooled atomics
__global__ __launch_bounds__(256) void k_gemm2(
    const ushort_t* __restrict__ A, const float* __restrict__ W,
    const float* __restrict__ bias, float* __restrict__ pooled, int colofs,
    const int* __restrict__ batch, int n) {
    constexpr int R = 32;
    int col = threadIdx.x;                   // O2 == 256
    int row0 = blockIdx.x * R;               // grid sized so row0+R <= n (N%32==0)

    float acc[R];
#pragma unroll
    for (int r = 0; r < R; ++r) acc[r] = 0.f;

    const ushort_t* Ab = A + (size_t)row0 * FT2;
    for (int f0 = 0; f0 < FT2; f0 += 8) {
        float wv[8];
#pragma unroll
        for (int j = 0; j < 8; ++j) wv[j] = W[(f0 + j) * O2 + col];
#pragma unroll
        for (int r = 0; r < R; ++r) {
            const uint4 av = *(const uint4*)(Ab + (size_t)r * FT2 + f0);
            acc[r] = fmaf(bflo(av.x), wv[0], acc[r]);
            acc[r] = fmaf(bfhi(av.x), wv[1], acc[r]);
            acc[r] = fmaf(bflo(av.y), wv[2], acc[r]);
            acc[r] = fmaf(bfhi(av.y), wv[3], acc[r]);
            acc[r] = fmaf(bflo(av.z), wv[4], acc[r]);
            acc[r] = fmaf(bfhi(av.z), wv[5], acc[r]);
            acc[r] = fmaf(bflo(av.w), wv[6], acc[r]);
            acc[r] = fmaf(bfhi(av.w), wv[7], acc[r]);
        }
    }
    float b = bias[col];
    int g = batch[row0];
    float run = 0.f;
#pragma unroll
    for (int r = 0; r < R; ++r) {
        int row = row0 + r;
        if (row >= n) break;
        float v = fmaxf(acc[r] + b, 0.f);
        int gb = batch[row];
        if (gb != g) {
            atomicAdd(pooled + (size_t)g * 512 + colofs + col, run);
            run = 0.f;
            g = gb;
        }
        run += v;
    }
    atomicAdd(pooled + (size_t)g * 512 + colofs + col, run);
}

__global__ void k_logits(const float* __restrict__ pooled, const int* __restrict__ gstart,
                         const float* __restrict__ fcw, const float* __restrict__ fcb,
                         float* __restrict__ out) {
    int g = threadIdx.x;
    int cnt = gstart[g + 1] - gstart[g];
    float inv = 1.f / (float)(cnt > 1 ? cnt : 1);
    float lg[4];
#pragma unroll
    for (int o = 0; o < 4; ++o) lg[o] = fcb[o];
    for (int f = 0; f < 512; ++f) {
        float p = pooled[g * 512 + f] * inv;
#pragma unroll
        for (int o = 0; o < 4; ++o) lg[o] = fmaf(p, fcw[f * 4 + o], lg[o]);
    }
    float m = fmaxf(fmaxf(lg[0], lg[1]), fmaxf(lg[2], lg[3]));
    float s = 0.f;
#pragma unroll
    for (int o = 0; o < 4; ++o) s += expf(lg[o] - m);
    float l = logf(s);
#pragma unroll
    for (int o = 0; o < 4; ++o) out[g * 4 + o] = lg[o] - m - l;
}

// -------------------- launch --------------------

extern "C" void kernel_launch(void* const* d_in, const int* in_sizes, int n_in,
                              void* d_out, int out_size, void* d_ws, size_t ws_size,
                              hipStream_t stream) {
    const float* x   = (const float*)d_in[0];
    const int* ei    = (const int*)d_in[1];
    const int* batch = (const int*)d_in[2];
    const float* W11 = (const float*)d_in[3];
    const float* b11 = (const float*)d_in[4];
    const float* W12 = (const float*)d_in[5];
    const float* b12 = (const float*)d_in[6];
    const float* W21 = (const float*)d_in[7];
    const float* b21 = (const float*)d_in[8];
    const float* W22 = (const float*)d_in[9];
    const float* b22 = (const float*)d_in[10];
    const float* fcw = (const float*)d_in[11];
    const float* fcb = (const float*)d_in[12];
    float* out = (float*)d_out;

    const int N = in_sizes[0] / F1;
    const int E = in_sizes[1] / 2;
    const int* src = ei;
    const int* dst = ei + E;

    char* w = (char*)d_ws;
    size_t pos = 0;
    auto alloc = [&](size_t bytes) -> void* {
        void* p = w + pos;
        pos += (bytes + 255) & ~(size_t)255;
        return p;
    };
    int* cur_f   = (int*)alloc((size_t)N * 4);
    int* cur_r   = (int*)alloc((size_t)N * 4);
    int* off_f   = (int*)alloc((size_t)(N + 1) * 4);
    int* off_r   = (int*)alloc((size_t)(N + 1) * 4);
    float* dinvF = (float*)alloc((size_t)N * 4);
    float* dinvR = (float*)alloc((size_t)N * 4);
    int* nbr_f   = (int*)alloc((size_t)E * 4);
    float* w_f   = (float*)alloc((size_t)E * 4);
    int* nbr_r   = (int*)alloc((size_t)E * 4);
    float* w_r   = (float*)alloc((size_t)E * 4);
    int* blks_f  = (int*)alloc(1024);
    int* blks_r  = (int*)alloc(1024);
    int* gstart  = (int*)alloc((NGRAPH + 1) * 4);
    float* pooled = (float*)alloc((size_t)NGRAPH * 512 * 4);
    float* TxAll1 = (float*)alloc((size_t)N * FT1 * 4);          // 32 MB fp32
    ushort_t* TxAll2 = (ushort_t*)alloc((size_t)N * FT2 * 2);    // 128 MB bf16
    // total ~172.5 MB

    (void)hipMemsetAsync(cur_f, 0, (size_t)N * 4, stream);
    (void)hipMemsetAsync(cur_r, 0, (size_t)N * 4, stream);
    (void)hipMemsetAsync(pooled, 0, (size_t)NGRAPH * 512 * 4, stream);

    int gE = (E + 255) / 256, gN = (N + 255) / 256;
    k_count<<<gE, 256, 0, stream>>>(src, dst, cur_f, cur_r, E);
    k_dinv<<<gN, 256, 0, stream>>>(cur_f, cur_r, dinvF, dinvR, N);

    int NB = (N + 511) / 512;
    k_scan1<<<NB, 256, 0, stream>>>(cur_f, off_f, blks_f, N);
    k_scan1<<<NB, 256, 0, stream>>>(cur_r, off_r, blks_r, N);
    k_scan2<<<1, 256, 0, stream>>>(blks_f, NB);
    k_scan2<<<1, 256, 0, stream>>>(blks_r, NB);
    k_scan3<<<NB, 256, 0, stream>>>(off_f, blks_f, N);
    k_scan3<<<NB, 256, 0, stream>>>(off_r, blks_r, N);
    k_tail<<<1, 64, 0, stream>>>(off_f, off_r, N, E);
    (void)hipMemcpyAsync(cur_f, off_f, (size_t)N * 4, hipMemcpyDeviceToDevice, stream);
    (void)hipMemcpyAsync(cur_r, off_r, (size_t)N * 4, hipMemcpyDeviceToDevice, stream);
    k_scatter<<<gE, 256, 0, stream>>>(src, dst, dinvF, dinvR, cur_f, cur_r,
                                      nbr_f, w_f, nbr_r, w_r, E);
    k_gstart<<<5, 64, 0, stream>>>(batch, gstart, N);

    // ---------------- layer 1 (fp32 Tx, F=16) ----------------
    k_copyx<<<(N * 4 + 255) / 256, 256, 0, stream>>>(x, TxAll1, N);
    int gs1 = (N * 4 + 255) / 256;
    auto C1 = [&](int k) { return TxAll1 + k * F1; };
    // fwd
    k_spmm_f32<<<gs1, 256, 0, stream>>>(C1(0), C1(1), nullptr, off_f, nbr_f, w_f, N);
    k_spmm_f32<<<gs1, 256, 0, stream>>>(C1(1), C1(2), C1(0), off_f, nbr_f, w_f, N);
    k_spmm_f32<<<gs1, 256, 0, stream>>>(C1(2), C1(3), C1(1), off_f, nbr_f, w_f, N);
    k_spmm_f32<<<gs1, 256, 0, stream>>>(C1(3), C1(4), C1(2), off_f, nbr_f, w_f, N);
    k_gemm1<<<(N + 127) / 128, 256, 0, stream>>>(TxAll1, W11, b11, TxAll2, N);
    // rev (overwrites C1(1..4); C1(0)=x preserved)
    k_spmm_f32<<<gs1, 256, 0, stream>>>(C1(0), C1(1), nullptr, off_r, nbr_r, w_r, N);
    k_spmm_f32<<<gs1, 256, 0, stream>>>(C1(1), C1(2), C1(0), off_r, nbr_r, w_r, N);
    k_spmm_f32<<<gs1, 256, 0, stream>>>(C1(2), C1(3), C1(1), off_r, nbr_r, w_r, N);
    k_spmm_f32<<<gs1, 256, 0, stream>>>(C1(3), C1(4), C1(2), off_r, nbr_r, w_r, N);
    k_gemm1<<<(N + 127) / 128, 256, 0, stream>>>(TxAll1, W12, b12, TxAll2 + O1, N);

    // ---------------- layer 2 (bf16 Tx, F=128) ----------------
    int gs2 = (N * 16 + 255) / 256;
    auto C2 = [&](int k) { return TxAll2 + k * F2; };
    // fwd
    k_spmm_bf<<<gs2, 256, 0, stream>>>(C2(0), C2(1), nullptr, off_f, nbr_f, w_f, N);
    k_spmm_bf<<<gs2, 256, 0, stream>>>(C2(1), C2(2), C2(0), off_f, nbr_f, w_f, N);
    k_spmm_bf<<<gs2, 256, 0, stream>>>(C2(2), C2(3), C2(1), off_f, nbr_f, w_f, N);
    k_spmm_bf<<<gs2, 256, 0, stream>>>(C2(3), C2(4), C2(2), off_f, nbr_f, w_f, N);
    k_gemm2<<<(N + 31) / 32, 256, 0, stream>>>(TxAll2, W21, b21, pooled, 0, batch, N);
    // rev
    k_spmm_bf<<<gs2, 256, 0, stream>>>(C2(0), C2(1), nullptr, off_r, nbr_r, w_r, N);
    k_spmm_bf<<<gs2, 256, 0, stream>>>(C2(1), C2(2), C2(0), off_r, nbr_r, w_r, N);
    k_spmm_bf<<<gs2, 256, 0, stream>>>(C2(2), C2(3), C2(1), off_r, nbr_r, w_r, N);
    k_spmm_bf<<<gs2, 256, 0, stream>>>(C2(3), C2(4), C2(2), off_r, nbr_r, w_r, N);
    k_gemm2<<<(N + 31) / 32, 256, 0, stream>>>(TxAll2, W22, b22, pooled, 256, batch, N);

    k_logits<<<1, 256, 0, stream>>>(pooled, gstart, fcw, fcb, out);
}

// Round 4
// 987.725 us; speedup vs baseline: 3.1841x; 3.1841x over previous
//
#include <hip/hip_runtime.h>
#include <stdint.h>

#define NNODES 100000
#define NEDGES 600000
#define NGRAPH 256
#define KCH 5
#define F1 16
#define O1 64
#define F2 128
#define O2 256
#define FT1 (KCH * F1) /* 80  */
#define FT2 (KCH * F2) /* 640 */
#define KSTEPS 20      /* 640/32 */

typedef unsigned short ushort_t;
typedef __attribute__((ext_vector_type(8))) short bf16x8;
typedef __attribute__((ext_vector_type(4))) float f32x4;

__device__ __forceinline__ float bflo(unsigned int u) {
    union { unsigned int u; float f; } v; v.u = u << 16; return v.f;
}
__device__ __forceinline__ float bfhi(unsigned int u) {
    union { unsigned int u; float f; } v; v.u = u & 0xFFFF0000u; return v.f;
}
__device__ __forceinline__ unsigned int f2bf(float f) {
    union { float f; unsigned int u; } v; v.f = f;
    return (v.u + 0x7FFFu + ((v.u >> 16) & 1u)) >> 16;  // RNE
}
__device__ __forceinline__ unsigned int pack2(float lo, float hi) {
    return (f2bf(hi) << 16) | f2bf(lo);
}

// -------------------- CSR build --------------------

__global__ void k_count(const int* __restrict__ src, const int* __restrict__ dst,
                        int* __restrict__ cntDst, int* __restrict__ cntSrc, int E) {
    int e = blockIdx.x * 256 + threadIdx.x;
    if (e < E) {
        atomicAdd(&cntDst[dst[e]], 1);
        atomicAdd(&cntSrc[src[e]], 1);
    }
}

__global__ void k_dinv(const int* __restrict__ cntDst, const int* __restrict__ cntSrc,
                       float* __restrict__ dinvF, float* __restrict__ dinvR, int n) {
    int i = blockIdx.x * 256 + threadIdx.x;
    if (i < n) {
        int cs = cntSrc[i], cd = cntDst[i];
        dinvF[i] = cs > 0 ? rsqrtf((float)cs) : 0.f;  // deg over src -> fwd norm
        dinvR[i] = cd > 0 ? rsqrtf((float)cd) : 0.f;  // deg over dst -> rev norm
    }
}

// exclusive scan, 512 elems/block
__global__ void k_scan1(const int* __restrict__ in, int* __restrict__ out,
                        int* __restrict__ blksum, int n) {
    __shared__ int a[512];
    __shared__ int s[256];
    int t = threadIdx.x;
    int base = blockIdx.x * 512;
    a[t]       = (base + t < n)       ? in[base + t]       : 0;
    a[t + 256] = (base + t + 256 < n) ? in[base + t + 256] : 0;
    __syncthreads();
    s[t] = a[2 * t] + a[2 * t + 1];
    __syncthreads();
    for (int off = 1; off < 256; off <<= 1) {
        int v = (t >= off) ? s[t - off] : 0;
        __syncthreads();
        s[t] += v;
        __syncthreads();
    }
    int ep = (t > 0) ? s[t - 1] : 0;  // exclusive over pairs
    if (base + 2 * t < n)     out[base + 2 * t]     = ep;
    if (base + 2 * t + 1 < n) out[base + 2 * t + 1] = ep + a[2 * t];
    if (t == 255) blksum[blockIdx.x] = s[255];
}

__global__ void k_scan2(int* __restrict__ blksum, int nb) {
    __shared__ int s[256];
    int t = threadIdx.x;
    s[t] = (t < nb) ? blksum[t] : 0;
    __syncthreads();
    for (int off = 1; off < 256; off <<= 1) {
        int v = (t >= off) ? s[t - off] : 0;
        __syncthreads();
        s[t] += v;
        __syncthreads();
    }
    if (t < nb) blksum[t] = (t > 0) ? s[t - 1] : 0;
}

__global__ void k_scan3(int* __restrict__ out, const int* __restrict__ blksum, int n) {
    int i = blockIdx.x * 512 + threadIdx.x;
    int add = blksum[blockIdx.x];
    if (i < n) out[i] += add;
    if (i + 256 < n) out[i + 256] += add;
}

__global__ void k_tail(int* __restrict__ off_f, int* __restrict__ off_r, int n, int E) {
    if (threadIdx.x == 0) { off_f[n] = E; off_r[n] = E; }
}

__global__ void k_scatter(const int* __restrict__ src, const int* __restrict__ dst,
                          const float* __restrict__ dinvF, const float* __restrict__ dinvR,
                          int* __restrict__ curF, int* __restrict__ curR,
                          int* __restrict__ nbrF, float* __restrict__ wF,
                          int* __restrict__ nbrR, float* __restrict__ wR, int E) {
    int e = blockIdx.x * 256 + threadIdx.x;
    if (e < E) {
        int s = src[e], d = dst[e];
        int p = atomicAdd(&curF[d], 1);
        nbrF[p] = s;
        wF[p] = -dinvF[s] * dinvF[d];
        int q = atomicAdd(&curR[s], 1);
        nbrR[q] = d;
        wR[q] = -dinvR[s] * dinvR[d];
    }
}

__global__ void k_gstart(const int* __restrict__ batch, int* __restrict__ gstart, int n) {
    int g = blockIdx.x * 64 + threadIdx.x;
    if (g > NGRAPH) return;
    if (g == NGRAPH) { gstart[g] = n; return; }
    int lo = 0, hi = n;
    while (lo < hi) {
        int mid = (lo + hi) >> 1;
        if (batch[mid] < g) lo = mid + 1; else hi = mid;
    }
    gstart[g] = lo;
}

// -------------------- compute --------------------

__global__ void k_copyx(const float* __restrict__ x, float* __restrict__ Tx, int n) {
    int tid = blockIdx.x * 256 + threadIdx.x;
    int r = tid >> 2, c = tid & 3;
    if (r < n)
        *(float4*)(Tx + (size_t)r * FT1 + c * 4) =
            *(const float4*)(x + (size_t)r * 16 + c * 4);
}

// fp32 SpMM (layer 1, F=16): Hout[r] = 2*sum - Tx0[r]  (or sum when Tx0==null)
__global__ void k_spmm_f32(const float* __restrict__ Hin, float* __restrict__ Hout,
                           const float* __restrict__ Tx0,
                           const int* __restrict__ off, const int* __restrict__ nbr,
                           const float* __restrict__ wts, int n) {
    int tid = blockIdx.x * 256 + threadIdx.x;
    int r = tid >> 2, c = tid & 3;
    if (r >= n) return;
    int j0 = off[r], j1 = off[r + 1];
    float4 s = {0.f, 0.f, 0.f, 0.f};
    for (int j = j0; j < j1; ++j) {
        int nb = nbr[j];
        float w2 = wts[j];
        const float4 h = *(const float4*)(Hin + (size_t)nb * FT1 + c * 4);
        s.x += w2 * h.x; s.y += w2 * h.y; s.z += w2 * h.z; s.w += w2 * h.w;
    }
    float4 o;
    if (Tx0) {
        const float4 t0 = *(const float4*)(Tx0 + (size_t)r * FT1 + c * 4);
        o.x = 2.f * s.x - t0.x; o.y = 2.f * s.y - t0.y;
        o.z = 2.f * s.z - t0.z; o.w = 2.f * s.w - t0.w;
    } else {
        o = s;
    }
    *(float4*)(Hout + (size_t)r * FT1 + c * 4) = o;
}

// bf16 SpMM (layer 2, F=128): 16 lanes/row, 8 feats/lane (uint4 = 8 bf16)
__global__ void k_spmm_bf(const ushort_t* __restrict__ Hin, ushort_t* __restrict__ Hout,
                          const ushort_t* __restrict__ Tx0,
                          const int* __restrict__ off, const int* __restrict__ nbr,
                          const float* __restrict__ wts, int n) {
    int tid = blockIdx.x * 256 + threadIdx.x;
    int r = tid >> 4, c = tid & 15;
    if (r >= n) return;
    int j0 = off[r], j1 = off[r + 1];
    float s0 = 0.f, s1 = 0.f, s2 = 0.f, s3 = 0.f;
    float s4 = 0.f, s5 = 0.f, s6 = 0.f, s7 = 0.f;
    for (int j = j0; j < j1; ++j) {
        int nb = nbr[j];
        float w2 = wts[j];
        const uint4 hv = *(const uint4*)(Hin + (size_t)nb * FT2 + c * 8);
        s0 = fmaf(bflo(hv.x), w2, s0); s1 = fmaf(bfhi(hv.x), w2, s1);
        s2 = fmaf(bflo(hv.y), w2, s2); s3 = fmaf(bfhi(hv.y), w2, s3);
        s4 = fmaf(bflo(hv.z), w2, s4); s5 = fmaf(bfhi(hv.z), w2, s5);
        s6 = fmaf(bflo(hv.w), w2, s6); s7 = fmaf(bfhi(hv.w), w2, s7);
    }
    if (Tx0) {
        const uint4 t0 = *(const uint4*)(Tx0 + (size_t)r * FT2 + c * 8);
        s0 = 2.f * s0 - bflo(t0.x); s1 = 2.f * s1 - bfhi(t0.x);
        s2 = 2.f * s2 - bflo(t0.y); s3 = 2.f * s3 - bfhi(t0.y);
        s4 = 2.f * s4 - bflo(t0.z); s5 = 2.f * s5 - bfhi(t0.z);
        s6 = 2.f * s6 - bflo(t0.w); s7 = 2.f * s7 - bfhi(t0.w);
    }
    uint4 o;
    o.x = pack2(s0, s1); o.y = pack2(s2, s3);
    o.z = pack2(s4, s5); o.w = pack2(s6, s7);
    *(uint4*)(Hout + (size_t)r * FT2 + c * 8) = o;
}

// layer-1 GEMM: A fp32 [n,80] x W [80,64] -> bf16 out slice (ld=640), bias+relu
__global__ __launch_bounds__(256) void k_gemm1(
    const float* __restrict__ A, const float* __restrict__ W,
    const float* __restrict__ bias, ushort_t* __restrict__ out, int n) {
    constexpr int R = 32;
    int col = threadIdx.x & 63;
    int rg = threadIdx.x >> 6;               // wave index (wave-uniform)
    int row0 = blockIdx.x * 128 + rg * R;
    row0 = __builtin_amdgcn_readfirstlane(row0);
    if (row0 > n - R) row0 = n - R;          // clamp reads in-bounds (benign dup writes)

    float acc[R];
#pragma unroll
    for (int r = 0; r < R; ++r) acc[r] = 0.f;

    const float* Ab = A + (size_t)row0 * FT1;
    for (int f0 = 0; f0 < FT1; f0 += 8) {
        float wv[8];
#pragma unroll
        for (int j = 0; j < 8; ++j) wv[j] = W[(f0 + j) * O1 + col];
#pragma unroll
        for (int r = 0; r < R; ++r) {
            const float* ar = Ab + (size_t)r * FT1 + f0;
#pragma unroll
            for (int j = 0; j < 8; ++j) acc[r] = fmaf(ar[j], wv[j], acc[r]);
        }
    }
    float b = bias[col];
#pragma unroll
    for (int r = 0; r < R; ++r) {
        int row = row0 + r;
        out[(size_t)row * FT2 + col] = (ushort_t)f2bf(fmaxf(acc[r] + b, 0.f));
    }
}

// pack W [640,256] fp32 row-major -> bf16 MFMA B-fragment layout:
// Bp[((nt*KSTEPS + ks)*64 + lane)*8 + j] = bf16(W[ks*32 + (lane>>4)*8 + j][nt*16 + (lane&15)])
__global__ void k_packW(const float* __restrict__ W, ushort_t* __restrict__ Bp) {
    int tid = blockIdx.x * 256 + threadIdx.x;  // 16*KSTEPS*64 = 20480 threads
    if (tid >= 16 * KSTEPS * 64) return;
    int lane = tid & 63;
    int ks = (tid >> 6) % KSTEPS;
    int nt = tid / (64 * KSTEPS);
    int k0 = ks * 32 + (lane >> 4) * 8;
    int ncol = nt * 16 + (lane & 15);
    float v[8];
#pragma unroll
    for (int j = 0; j < 8; ++j) v[j] = W[(size_t)(k0 + j) * O2 + ncol];
    uint4 o;
    o.x = pack2(v[0], v[1]); o.y = pack2(v[2], v[3]);
    o.z = pack2(v[4], v[5]); o.w = pack2(v[6], v[7]);
    *(uint4*)(Bp + (size_t)tid * 8) = o;
}

// layer-2 MFMA GEMM: A bf16 [n,640] x Bp (packed W, bf16) -> relu(+bias) -> pooled sums.
// Block = 4 waves, 64 rows x 256 cols; wave w: cols [w*64, w*64+64), 4x4 mfma tiles.
__global__ __launch_bounds__(256) void k_gemm2_mfma(
    const ushort_t* __restrict__ A, const ushort_t* __restrict__ Bp,
    const float* __restrict__ bias, float* __restrict__ pooled, int colofs,
    const int* __restrict__ batch, int n) {
    int lane = threadIdx.x & 63;
    int wv = threadIdx.x >> 6;
    int m0 = blockIdx.x * 64;
    int mrow = lane & 15;
    int quad = lane >> 4;

    f32x4 acc[4][4] = {};  // [mfrag][nfrag]

    for (int ks = 0; ks < KSTEPS; ++ks) {
        int k0 = ks * 32;
        bf16x8 af[4];
#pragma unroll
        for (int mf = 0; mf < 4; ++mf)
            af[mf] = *(const bf16x8*)(A + (size_t)(m0 + mf * 16 + mrow) * FT2 + k0 + quad * 8);
        bf16x8 bfr[4];
#pragma unroll
        for (int nf = 0; nf < 4; ++nf) {
            int nt = wv * 4 + nf;
            bfr[nf] = *(const bf16x8*)(Bp + ((size_t)(nt * KSTEPS + ks) * 64 + lane) * 8);
        }
#pragma unroll
        for (int mf = 0; mf < 4; ++mf)
#pragma unroll
            for (int nf = 0; nf < 4; ++nf)
                acc[mf][nf] = __builtin_amdgcn_mfma_f32_16x16x32_bf16(
                    af[mf], bfr[nf], acc[mf][nf], 0, 0, 0);
    }

    // epilogue: C/D layout col=lane&15, row=quad*4+reg; pool into pooled[g*512+colofs+col]
    float bcol[4];
#pragma unroll
    for (int nf = 0; nf < 4; ++nf) bcol[nf] = bias[wv * 64 + nf * 16 + mrow];

#pragma unroll
    for (int mf = 0; mf < 4; ++mf) {
        int t0 = m0 + mf * 16;
        if (t0 >= n) break;
        int te = (t0 + 15 < n) ? t0 + 15 : n - 1;
        int r0 = t0 + quad * 4;
        if (batch[t0] == batch[te]) {
            // whole 16-row tile in one graph: cross-quad reduce, 1 atomic / (nf, col)
            int g = batch[t0];
#pragma unroll
            for (int nf = 0; nf < 4; ++nf) {
                float s = 0.f;
#pragma unroll
                for (int reg = 0; reg < 4; ++reg) {
                    float v = fmaxf(acc[mf][nf][reg] + bcol[nf], 0.f);
                    if (r0 + reg < n) s += v;
                }
                s += __shfl_xor(s, 16, 64);
                s += __shfl_xor(s, 32, 64);
                if (quad == 0)
                    atomicAdd(pooled + (size_t)g * 512 + colofs + wv * 64 + nf * 16 + mrow, s);
            }
        } else {
            // boundary tile: per-lane run merge over 4 consecutive rows
            int gb[4];
#pragma unroll
            for (int reg = 0; reg < 4; ++reg)
                gb[reg] = batch[(r0 + reg < n) ? r0 + reg : n - 1];
#pragma unroll
            for (int nf = 0; nf < 4; ++nf) {
                int col = colofs + wv * 64 + nf * 16 + mrow;
                float run = 0.f;
                int g = gb[0];
                bool any = false;
#pragma unroll
                for (int reg = 0; reg < 4; ++reg) {
                    int row = r0 + reg;
                    if (row >= n) break;
                    float v = fmaxf(acc[mf][nf][reg] + bcol[nf], 0.f);
                    if (gb[reg] != g) {
                        atomicAdd(pooled + (size_t)g * 512 + col, run);
                        run = 0.f;
                        g = gb[reg];
                    }
                    run += v;
                    any = true;
                }
                if (any) atomicAdd(pooled + (size_t)g * 512 + col, run);
            }
        }
    }
}

__global__ void k_logits(const float* __restrict__ pooled, const int* __restrict__ gstart,
                         const float* __restrict__ fcw, const float* __restrict__ fcb,
                         float* __restrict__ out) {
    int g = threadIdx.x;
    int cnt = gstart[g + 1] - gstart[g];
    float inv = 1.f / (float)(cnt > 1 ? cnt : 1);
    float lg[4];
#pragma unroll
    for (int o = 0; o < 4; ++o) lg[o] = fcb[o];
    for (int f = 0; f < 512; ++f) {
        float p = pooled[g * 512 + f] * inv;
#pragma unroll
        for (int o = 0; o < 4; ++o) lg[o] = fmaf(p, fcw[f * 4 + o], lg[o]);
    }
    float m = fmaxf(fmaxf(lg[0], lg[1]), fmaxf(lg[2], lg[3]));
    float s = 0.f;
#pragma unroll
    for (int o = 0; o < 4; ++o) s += expf(lg[o] - m);
    float l = logf(s);
#pragma unroll
    for (int o = 0; o < 4; ++o) out[g * 4 + o] = lg[o] - m - l;
}

// -------------------- launch --------------------

extern "C" void kernel_launch(void* const* d_in, const int* in_sizes, int n_in,
                              void* d_out, int out_size, void* d_ws, size_t ws_size,
                              hipStream_t stream) {
    const float* x   = (const float*)d_in[0];
    const int* ei    = (const int*)d_in[1];
    const int* batch = (const int*)d_in[2];
    const float* W11 = (const float*)d_in[3];
    const float* b11 = (const float*)d_in[4];
    const float* W12 = (const float*)d_in[5];
    const float* b12 = (const float*)d_in[6];
    const float* W21 = (const float*)d_in[7];
    const float* b21 = (const float*)d_in[8];
    const float* W22 = (const float*)d_in[9];
    const float* b22 = (const float*)d_in[10];
    const float* fcw = (const float*)d_in[11];
    const float* fcb = (const float*)d_in[12];
    float* out = (float*)d_out;

    const int N = in_sizes[0] / F1;
    const int E = in_sizes[1] / 2;
    const int* src = ei;
    const int* dst = ei + E;

    char* w = (char*)d_ws;
    size_t pos = 0;
    auto alloc = [&](size_t bytes) -> void* {
        void* p = w + pos;
        pos += (bytes + 255) & ~(size_t)255;
        return p;
    };
    int* cur_f   = (int*)alloc((size_t)N * 4);
    int* cur_r   = (int*)alloc((size_t)N * 4);
    int* off_f   = (int*)alloc((size_t)(N + 1) * 4);
    int* off_r   = (int*)alloc((size_t)(N + 1) * 4);
    float* dinvF = (float*)alloc((size_t)N * 4);
    float* dinvR = (float*)alloc((size_t)N * 4);
    int* nbr_f   = (int*)alloc((size_t)E * 4);
    float* w_f   = (float*)alloc((size_t)E * 4);
    int* nbr_r   = (int*)alloc((size_t)E * 4);
    float* w_r   = (float*)alloc((size_t)E * 4);
    int* blks_f  = (int*)alloc(1024);
    int* blks_r  = (int*)alloc(1024);
    int* gstart  = (int*)alloc((NGRAPH + 1) * 4);
    float* pooled = (float*)alloc((size_t)NGRAPH * 512 * 4);
    ushort_t* BpF = (ushort_t*)alloc((size_t)FT2 * O2 * 2);      // 320 KB packed W21
    ushort_t* BpR = (ushort_t*)alloc((size_t)FT2 * O2 * 2);      // 320 KB packed W22
    float* TxAll1 = (float*)alloc((size_t)N * FT1 * 4);          // 32 MB fp32
    ushort_t* TxAll2 = (ushort_t*)alloc((size_t)(N + 64) * FT2 * 2);  // 128 MB bf16 + pad
    // total ~173.4 MB

    (void)hipMemsetAsync(cur_f, 0, (size_t)N * 4, stream);
    (void)hipMemsetAsync(cur_r, 0, (size_t)N * 4, stream);
    (void)hipMemsetAsync(pooled, 0, (size_t)NGRAPH * 512 * 4, stream);

    int gE = (E + 255) / 256, gN = (N + 255) / 256;
    k_count<<<gE, 256, 0, stream>>>(src, dst, cur_f, cur_r, E);
    k_dinv<<<gN, 256, 0, stream>>>(cur_f, cur_r, dinvF, dinvR, N);

    int NB = (N + 511) / 512;
    k_scan1<<<NB, 256, 0, stream>>>(cur_f, off_f, blks_f, N);
    k_scan1<<<NB, 256, 0, stream>>>(cur_r, off_r, blks_r, N);
    k_scan2<<<1, 256, 0, stream>>>(blks_f, NB);
    k_scan2<<<1, 256, 0, stream>>>(blks_r, NB);
    k_scan3<<<NB, 256, 0, stream>>>(off_f, blks_f, N);
    k_scan3<<<NB, 256, 0, stream>>>(off_r, blks_r, N);
    k_tail<<<1, 64, 0, stream>>>(off_f, off_r, N, E);
    (void)hipMemcpyAsync(cur_f, off_f, (size_t)N * 4, hipMemcpyDeviceToDevice, stream);
    (void)hipMemcpyAsync(cur_r, off_r, (size_t)N * 4, hipMemcpyDeviceToDevice, stream);
    k_scatter<<<gE, 256, 0, stream>>>(src, dst, dinvF, dinvR, cur_f, cur_r,
                                      nbr_f, w_f, nbr_r, w_r, E);
    k_gstart<<<5, 64, 0, stream>>>(batch, gstart, N);
    k_packW<<<80, 256, 0, stream>>>(W21, BpF);
    k_packW<<<80, 256, 0, stream>>>(W22, BpR);

    // ---------------- layer 1 (fp32 Tx, F=16) ----------------
    k_copyx<<<(N * 4 + 255) / 256, 256, 0, stream>>>(x, TxAll1, N);
    int gs1 = (N * 4 + 255) / 256;
    auto C1 = [&](int k) { return TxAll1 + k * F1; };
    // fwd
    k_spmm_f32<<<gs1, 256, 0, stream>>>(C1(0), C1(1), nullptr, off_f, nbr_f, w_f, N);
    k_spmm_f32<<<gs1, 256, 0, stream>>>(C1(1), C1(2), C1(0), off_f, nbr_f, w_f, N);
    k_spmm_f32<<<gs1, 256, 0, stream>>>(C1(2), C1(3), C1(1), off_f, nbr_f, w_f, N);
    k_spmm_f32<<<gs1, 256, 0, stream>>>(C1(3), C1(4), C1(2), off_f, nbr_f, w_f, N);
    k_gemm1<<<(N + 127) / 128, 256, 0, stream>>>(TxAll1, W11, b11, TxAll2, N);
    // rev (overwrites C1(1..4); C1(0)=x preserved)
    k_spmm_f32<<<gs1, 256, 0, stream>>>(C1(0), C1(1), nullptr, off_r, nbr_r, w_r, N);
    k_spmm_f32<<<gs1, 256, 0, stream>>>(C1(1), C1(2), C1(0), off_r, nbr_r, w_r, N);
    k_spmm_f32<<<gs1, 256, 0, stream>>>(C1(2), C1(3), C1(1), off_r, nbr_r, w_r, N);
    k_spmm_f32<<<gs1, 256, 0, stream>>>(C1(3), C1(4), C1(2), off_r, nbr_r, w_r, N);
    k_gemm1<<<(N + 127) / 128, 256, 0, stream>>>(TxAll1, W12, b12, TxAll2 + O1, N);

    // ---------------- layer 2 (bf16 Tx, F=128) ----------------
    int gs2 = (N * 16 + 255) / 256;
    auto C2 = [&](int k) { return TxAll2 + k * F2; };
    int gg = (N + 63) / 64;
    // fwd
    k_spmm_bf<<<gs2, 256, 0, stream>>>(C2(0), C2(1), nullptr, off_f, nbr_f, w_f, N);
    k_spmm_bf<<<gs2, 256, 0, stream>>>(C2(1), C2(2), C2(0), off_f, nbr_f, w_f, N);
    k_spmm_bf<<<gs2, 256, 0, stream>>>(C2(2), C2(3), C2(1), off_f, nbr_f, w_f, N);
    k_spmm_bf<<<gs2, 256, 0, stream>>>(C2(3), C2(4), C2(2), off_f, nbr_f, w_f, N);
    k_gemm2_mfma<<<gg, 256, 0, stream>>>(TxAll2, BpF, b21, pooled, 0, batch, N);
    // rev
    k_spmm_bf<<<gs2, 256, 0, stream>>>(C2(0), C2(1), nullptr, off_r, nbr_r, w_r, N);
    k_spmm_bf<<<gs2, 256, 0, stream>>>(C2(1), C2(2), C2(0), off_r, nbr_r, w_r, N);
    k_spmm_bf<<<gs2, 256, 0, stream>>>(C2(2), C2(3), C2(1), off_r, nbr_r, w_r, N);
    k_spmm_bf<<<gs2, 256, 0, stream>>>(C2(3), C2(4), C2(2), off_r, nbr_r, w_r, N);
    k_gemm2_mfma<<<gg, 256, 0, stream>>>(TxAll2, BpR, b22, pooled, 256, batch, N);

    k_logits<<<1, 256, 0, stream>>>(pooled, gstart, fcw, fcb, out);
}

// Round 5
// 907.555 us; speedup vs baseline: 3.4654x; 1.0883x over previous
//
#include <hip/hip_runtime.h>
#include <stdint.h>

#define NNODES 100000
#define NEDGES 600000
#define NGRAPH 256
#define KCH 5
#define F1 16
#define O1 64
#define F2 128
#define O2 256
#define FT1 (KCH * F1) /* 80  */
#define FT2 (KCH * F2) /* 640 */
#define KSTEPS 20      /* 640/32 */

typedef unsigned short ushort_t;
typedef __attribute__((ext_vector_type(8))) short bf16x8;
typedef __attribute__((ext_vector_type(4))) float f32x4;

__device__ __forceinline__ float bflo(unsigned int u) {
    union { unsigned int u; float f; } v; v.u = u << 16; return v.f;
}
__device__ __forceinline__ float bfhi(unsigned int u) {
    union { unsigned int u; float f; } v; v.u = u & 0xFFFF0000u; return v.f;
}
__device__ __forceinline__ unsigned int f2bf(float f) {
    union { float f; unsigned int u; } v; v.f = f;
    return (v.u + 0x7FFFu + ((v.u >> 16) & 1u)) >> 16;  // RNE
}
__device__ __forceinline__ unsigned int pack2(float lo, float hi) {
    return (f2bf(hi) << 16) | f2bf(lo);
}

// -------------------- CSR build --------------------

__global__ void k_count(const int* __restrict__ src, const int* __restrict__ dst,
                        int* __restrict__ cntDst, int* __restrict__ cntSrc, int E) {
    int e = blockIdx.x * 256 + threadIdx.x;
    if (e < E) {
        atomicAdd(&cntDst[dst[e]], 1);
        atomicAdd(&cntSrc[src[e]], 1);
    }
}

__global__ void k_dinv(const int* __restrict__ cntDst, const int* __restrict__ cntSrc,
                       float* __restrict__ dinvF, float* __restrict__ dinvR, int n) {
    int i = blockIdx.x * 256 + threadIdx.x;
    if (i < n) {
        int cs = cntSrc[i], cd = cntDst[i];
        dinvF[i] = cs > 0 ? rsqrtf((float)cs) : 0.f;  // deg over src -> fwd norm
        dinvR[i] = cd > 0 ? rsqrtf((float)cd) : 0.f;  // deg over dst -> rev norm
    }
}

// exclusive scan, 512 elems/block
__global__ void k_scan1(const int* __restrict__ in, int* __restrict__ out,
                        int* __restrict__ blksum, int n) {
    __shared__ int a[512];
    __shared__ int s[256];
    int t = threadIdx.x;
    int base = blockIdx.x * 512;
    a[t]       = (base + t < n)       ? in[base + t]       : 0;
    a[t + 256] = (base + t + 256 < n) ? in[base + t + 256] : 0;
    __syncthreads();
    s[t] = a[2 * t] + a[2 * t + 1];
    __syncthreads();
    for (int off = 1; off < 256; off <<= 1) {
        int v = (t >= off) ? s[t - off] : 0;
        __syncthreads();
        s[t] += v;
        __syncthreads();
    }
    int ep = (t > 0) ? s[t - 1] : 0;  // exclusive over pairs
    if (base + 2 * t < n)     out[base + 2 * t]     = ep;
    if (base + 2 * t + 1 < n) out[base + 2 * t + 1] = ep + a[2 * t];
    if (t == 255) blksum[blockIdx.x] = s[255];
}

__global__ void k_scan2(int* __restrict__ blksum, int nb) {
    __shared__ int s[256];
    int t = threadIdx.x;
    s[t] = (t < nb) ? blksum[t] : 0;
    __syncthreads();
    for (int off = 1; off < 256; off <<= 1) {
        int v = (t >= off) ? s[t - off] : 0;
        __syncthreads();
        s[t] += v;
        __syncthreads();
    }
    if (t < nb) blksum[t] = (t > 0) ? s[t - 1] : 0;
}

__global__ void k_scan3(int* __restrict__ out, const int* __restrict__ blksum, int n) {
    int i = blockIdx.x * 512 + threadIdx.x;
    int add = blksum[blockIdx.x];
    if (i < n) out[i] += add;
    if (i + 256 < n) out[i + 256] += add;
}

__global__ void k_tail(int* __restrict__ off_f, int* __restrict__ off_r, int n, int E) {
    if (threadIdx.x == 0) { off_f[n] = E; off_r[n] = E; }
}

__global__ void k_scatter(const int* __restrict__ src, const int* __restrict__ dst,
                          const float* __restrict__ dinvF, const float* __restrict__ dinvR,
                          int* __restrict__ curF, int* __restrict__ curR,
                          int* __restrict__ nbrF, float* __restrict__ wF,
                          int* __restrict__ nbrR, float* __restrict__ wR, int E) {
    int e = blockIdx.x * 256 + threadIdx.x;
    if (e < E) {
        int s = src[e], d = dst[e];
        int p = atomicAdd(&curF[d], 1);
        nbrF[p] = s;
        wF[p] = -dinvF[s] * dinvF[d];
        int q = atomicAdd(&curR[s], 1);
        nbrR[q] = d;
        wR[q] = -dinvR[s] * dinvR[d];
    }
}

__global__ void k_gstart(const int* __restrict__ batch, int* __restrict__ gstart, int n) {
    int g = blockIdx.x * 64 + threadIdx.x;
    if (g > NGRAPH) return;
    if (g == NGRAPH) { gstart[g] = n; return; }
    int lo = 0, hi = n;
    while (lo < hi) {
        int mid = (lo + hi) >> 1;
        if (batch[mid] < g) lo = mid + 1; else hi = mid;
    }
    gstart[g] = lo;
}

// -------------------- compute --------------------

__global__ void k_copyx(const float* __restrict__ x, float* __restrict__ Tx, int n) {
    int tid = blockIdx.x * 256 + threadIdx.x;
    int r = tid >> 2, c = tid & 3;
    if (r < n)
        *(float4*)(Tx + (size_t)r * FT1 + c * 4) =
            *(const float4*)(x + (size_t)r * 16 + c * 4);
}

// fp32 SpMM (layer 1, F=16), edge-loop unrolled x4 for MLP
__global__ void k_spmm_f32(const float* __restrict__ Hin, float* __restrict__ Hout,
                           const float* __restrict__ Tx0,
                           const int* __restrict__ off, const int* __restrict__ nbr,
                           const float* __restrict__ wts, int n) {
    int tid = blockIdx.x * 256 + threadIdx.x;
    int r = tid >> 2, c = tid & 3;
    if (r >= n) return;
    int j0 = off[r], j1 = off[r + 1];
    float4 s = {0.f, 0.f, 0.f, 0.f};
    int j = j0;
    for (; j + 4 <= j1; j += 4) {
        int nb0 = nbr[j], nb1 = nbr[j + 1], nb2 = nbr[j + 2], nb3 = nbr[j + 3];
        float wa = wts[j], wb = wts[j + 1], wc = wts[j + 2], wd = wts[j + 3];
        const float4 h0 = *(const float4*)(Hin + (size_t)nb0 * FT1 + c * 4);
        const float4 h1 = *(const float4*)(Hin + (size_t)nb1 * FT1 + c * 4);
        const float4 h2 = *(const float4*)(Hin + (size_t)nb2 * FT1 + c * 4);
        const float4 h3 = *(const float4*)(Hin + (size_t)nb3 * FT1 + c * 4);
        s.x += wa * h0.x; s.y += wa * h0.y; s.z += wa * h0.z; s.w += wa * h0.w;
        s.x += wb * h1.x; s.y += wb * h1.y; s.z += wb * h1.z; s.w += wb * h1.w;
        s.x += wc * h2.x; s.y += wc * h2.y; s.z += wc * h2.z; s.w += wc * h2.w;
        s.x += wd * h3.x; s.y += wd * h3.y; s.z += wd * h3.z; s.w += wd * h3.w;
    }
    for (; j < j1; ++j) {
        int nb = nbr[j];
        float w2 = wts[j];
        const float4 h = *(const float4*)(Hin + (size_t)nb * FT1 + c * 4);
        s.x += w2 * h.x; s.y += w2 * h.y; s.z += w2 * h.z; s.w += w2 * h.w;
    }
    float4 o;
    if (Tx0) {
        const float4 t0 = *(const float4*)(Tx0 + (size_t)r * FT1 + c * 4);
        o.x = 2.f * s.x - t0.x; o.y = 2.f * s.y - t0.y;
        o.z = 2.f * s.z - t0.z; o.w = 2.f * s.w - t0.w;
    } else {
        o = s;
    }
    *(float4*)(Hout + (size_t)r * FT1 + c * 4) = o;
}

// bf16 SpMM (layer 2, F=128): 16 lanes/row, 8 feats/lane; edge loop unrolled x4
__global__ void k_spmm_bf(const ushort_t* __restrict__ Hin, ushort_t* __restrict__ Hout,
                          const ushort_t* __restrict__ Tx0,
                          const int* __restrict__ off, const int* __restrict__ nbr,
                          const float* __restrict__ wts, int n) {
    int tid = blockIdx.x * 256 + threadIdx.x;
    int r = tid >> 4, c = tid & 15;
    if (r >= n) return;
    int j0 = off[r], j1 = off[r + 1];
    float s0 = 0.f, s1 = 0.f, s2 = 0.f, s3 = 0.f;
    float s4 = 0.f, s5 = 0.f, s6 = 0.f, s7 = 0.f;
    int j = j0;
    for (; j + 4 <= j1; j += 4) {
        int nb0 = nbr[j], nb1 = nbr[j + 1], nb2 = nbr[j + 2], nb3 = nbr[j + 3];
        float wa = wts[j], wb = wts[j + 1], wc = wts[j + 2], wd = wts[j + 3];
        const uint4 h0 = *(const uint4*)(Hin + (size_t)nb0 * FT2 + c * 8);
        const uint4 h1 = *(const uint4*)(Hin + (size_t)nb1 * FT2 + c * 8);
        const uint4 h2 = *(const uint4*)(Hin + (size_t)nb2 * FT2 + c * 8);
        const uint4 h3 = *(const uint4*)(Hin + (size_t)nb3 * FT2 + c * 8);
        s0 = fmaf(bflo(h0.x), wa, s0); s1 = fmaf(bfhi(h0.x), wa, s1);
        s2 = fmaf(bflo(h0.y), wa, s2); s3 = fmaf(bfhi(h0.y), wa, s3);
        s4 = fmaf(bflo(h0.z), wa, s4); s5 = fmaf(bfhi(h0.z), wa, s5);
        s6 = fmaf(bflo(h0.w), wa, s6); s7 = fmaf(bfhi(h0.w), wa, s7);
        s0 = fmaf(bflo(h1.x), wb, s0); s1 = fmaf(bfhi(h1.x), wb, s1);
        s2 = fmaf(bflo(h1.y), wb, s2); s3 = fmaf(bfhi(h1.y), wb, s3);
        s4 = fmaf(bflo(h1.z), wb, s4); s5 = fmaf(bfhi(h1.z), wb, s5);
        s6 = fmaf(bflo(h1.w), wb, s6); s7 = fmaf(bfhi(h1.w), wb, s7);
        s0 = fmaf(bflo(h2.x), wc, s0); s1 = fmaf(bfhi(h2.x), wc, s1);
        s2 = fmaf(bflo(h2.y), wc, s2); s3 = fmaf(bfhi(h2.y), wc, s3);
        s4 = fmaf(bflo(h2.z), wc, s4); s5 = fmaf(bfhi(h2.z), wc, s5);
        s6 = fmaf(bflo(h2.w), wc, s6); s7 = fmaf(bfhi(h2.w), wc, s7);
        s0 = fmaf(bflo(h3.x), wd, s0); s1 = fmaf(bfhi(h3.x), wd, s1);
        s2 = fmaf(bflo(h3.y), wd, s2); s3 = fmaf(bfhi(h3.y), wd, s3);
        s4 = fmaf(bflo(h3.z), wd, s4); s5 = fmaf(bfhi(h3.z), wd, s5);
        s6 = fmaf(bflo(h3.w), wd, s6); s7 = fmaf(bfhi(h3.w), wd, s7);
    }
    for (; j < j1; ++j) {
        int nb = nbr[j];
        float w2 = wts[j];
        const uint4 hv = *(const uint4*)(Hin + (size_t)nb * FT2 + c * 8);
        s0 = fmaf(bflo(hv.x), w2, s0); s1 = fmaf(bfhi(hv.x), w2, s1);
        s2 = fmaf(bflo(hv.y), w2, s2); s3 = fmaf(bfhi(hv.y), w2, s3);
        s4 = fmaf(bflo(hv.z), w2, s4); s5 = fmaf(bfhi(hv.z), w2, s5);
        s6 = fmaf(bflo(hv.w), w2, s6); s7 = fmaf(bfhi(hv.w), w2, s7);
    }
    if (Tx0) {
        const uint4 t0 = *(const uint4*)(Tx0 + (size_t)r * FT2 + c * 8);
        s0 = 2.f * s0 - bflo(t0.x); s1 = 2.f * s1 - bfhi(t0.x);
        s2 = 2.f * s2 - bflo(t0.y); s3 = 2.f * s3 - bfhi(t0.y);
        s4 = 2.f * s4 - bflo(t0.z); s5 = 2.f * s5 - bfhi(t0.z);
        s6 = 2.f * s6 - bflo(t0.w); s7 = 2.f * s7 - bfhi(t0.w);
    }
    uint4 o;
    o.x = pack2(s0, s1); o.y = pack2(s2, s3);
    o.z = pack2(s4, s5); o.w = pack2(s6, s7);
    *(uint4*)(Hout + (size_t)r * FT2 + c * 8) = o;
}

// layer-1 GEMM: A fp32 [n,80] x W [80,64] -> bf16 out slice (ld=640), bias+relu
__global__ __launch_bounds__(256) void k_gemm1(
    const float* __restrict__ A, const float* __restrict__ W,
    const float* __restrict__ bias, ushort_t* __restrict__ out, int n) {
    constexpr int R = 32;
    int col = threadIdx.x & 63;
    int rg = threadIdx.x >> 6;               // wave index (wave-uniform)
    int row0 = blockIdx.x * 128 + rg * R;
    row0 = __builtin_amdgcn_readfirstlane(row0);
    if (row0 > n - R) row0 = n - R;          // clamp reads in-bounds (benign dup writes)

    float acc[R];
#pragma unroll
    for (int r = 0; r < R; ++r) acc[r] = 0.f;

    const float* Ab = A + (size_t)row0 * FT1;
    for (int f0 = 0; f0 < FT1; f0 += 8) {
        float wv[8];
#pragma unroll
        for (int j = 0; j < 8; ++j) wv[j] = W[(f0 + j) * O1 + col];
#pragma unroll
        for (int r = 0; r < R; ++r) {
            const float* ar = Ab + (size_t)r * FT1 + f0;
#pragma unroll
            for (int j = 0; j < 8; ++j) acc[r] = fmaf(ar[j], wv[j], acc[r]);
        }
    }
    float b = bias[col];
#pragma unroll
    for (int r = 0; r < R; ++r) {
        int row = row0 + r;
        out[(size_t)row * FT2 + col] = (ushort_t)f2bf(fmaxf(acc[r] + b, 0.f));
    }
}

// pack W [640,256] fp32 row-major -> bf16 MFMA B-fragment layout
__global__ void k_packW(const float* __restrict__ W, ushort_t* __restrict__ Bp) {
    int tid = blockIdx.x * 256 + threadIdx.x;  // 16*KSTEPS*64 = 20480 threads
    if (tid >= 16 * KSTEPS * 64) return;
    int lane = tid & 63;
    int ks = (tid >> 6) % KSTEPS;
    int nt = tid / (64 * KSTEPS);
    int k0 = ks * 32 + (lane >> 4) * 8;
    int ncol = nt * 16 + (lane & 15);
    float v[8];
#pragma unroll
    for (int j = 0; j < 8; ++j) v[j] = W[(size_t)(k0 + j) * O2 + ncol];
    uint4 o;
    o.x = pack2(v[0], v[1]); o.y = pack2(v[2], v[3]);
    o.z = pack2(v[4], v[5]); o.w = pack2(v[6], v[7]);
    *(uint4*)(Bp + (size_t)tid * 8) = o;
}

// layer-2 MFMA GEMM with 2-stage software pipeline (ping-pong register fragments)
__global__ __launch_bounds__(256) void k_gemm2_mfma(
    const ushort_t* __restrict__ A, const ushort_t* __restrict__ Bp,
    const float* __restrict__ bias, float* __restrict__ pooled, int colofs,
    const int* __restrict__ batch, int n) {
    int lane = threadIdx.x & 63;
    int wv = threadIdx.x >> 6;
    int m0 = blockIdx.x * 64;
    int mrow = lane & 15;
    int quad = lane >> 4;

    f32x4 acc[4][4] = {};  // [mfrag][nfrag]

    const ushort_t* Abase = A + (size_t)(m0 + mrow) * FT2 + quad * 8;
    const ushort_t* Bbase = Bp + ((size_t)(wv * 4) * KSTEPS * 64 + lane) * 8;

#define LOADFRAG(AF, BF, KS)                                                     \
    {                                                                            \
        int k0_ = (KS) * 32;                                                     \
        _Pragma("unroll")                                                        \
        for (int mf = 0; mf < 4; ++mf)                                           \
            AF[mf] = *(const bf16x8*)(Abase + (size_t)(mf * 16) * FT2 + k0_);    \
        _Pragma("unroll")                                                        \
        for (int nf = 0; nf < 4; ++nf)                                           \
            BF[nf] = *(const bf16x8*)(Bbase + ((size_t)nf * KSTEPS + (KS)) * 64 * 8); \
    }
#define DOMFMA(AF, BF)                                                           \
    {                                                                            \
        _Pragma("unroll")                                                        \
        for (int mf = 0; mf < 4; ++mf) {                                         \
            _Pragma("unroll")                                                    \
            for (int nf = 0; nf < 4; ++nf)                                       \
                acc[mf][nf] = __builtin_amdgcn_mfma_f32_16x16x32_bf16(           \
                    AF[mf], BF[nf], acc[mf][nf], 0, 0, 0);                       \
        }                                                                        \
    }

    bf16x8 afA[4], bfA[4], afB[4], bfB[4];
    LOADFRAG(afA, bfA, 0);
    for (int ks = 0; ks < KSTEPS; ks += 2) {
        LOADFRAG(afB, bfB, ks + 1);
        DOMFMA(afA, bfA);
        if (ks + 2 < KSTEPS) LOADFRAG(afA, bfA, ks + 2);
        DOMFMA(afB, bfB);
    }
#undef LOADFRAG
#undef DOMFMA

    // epilogue: C/D layout col=lane&15, row=quad*4+reg; pool into pooled[g*512+colofs+col]
    float bcol[4];
#pragma unroll
    for (int nf = 0; nf < 4; ++nf) bcol[nf] = bias[wv * 64 + nf * 16 + mrow];

#pragma unroll
    for (int mf = 0; mf < 4; ++mf) {
        int t0 = m0 + mf * 16;
        if (t0 >= n) break;
        int te = (t0 + 15 < n) ? t0 + 15 : n - 1;
        int r0 = t0 + quad * 4;
        if (batch[t0] == batch[te]) {
            // whole 16-row tile in one graph: cross-quad reduce, 1 atomic / (nf, col)
            int g = batch[t0];
#pragma unroll
            for (int nf = 0; nf < 4; ++nf) {
                float s = 0.f;
#pragma unroll
                for (int reg = 0; reg < 4; ++reg) {
                    float v = fmaxf(acc[mf][nf][reg] + bcol[nf], 0.f);
                    if (r0 + reg < n) s += v;
                }
                s += __shfl_xor(s, 16, 64);
                s += __shfl_xor(s, 32, 64);
                if (quad == 0)
                    atomicAdd(pooled + (size_t)g * 512 + colofs + wv * 64 + nf * 16 + mrow, s);
            }
        } else {
            // boundary tile: per-lane run merge over 4 consecutive rows
            int gb[4];
#pragma unroll
            for (int reg = 0; reg < 4; ++reg)
                gb[reg] = batch[(r0 + reg < n) ? r0 + reg : n - 1];
#pragma unroll
            for (int nf = 0; nf < 4; ++nf) {
                int col = colofs + wv * 64 + nf * 16 + mrow;
                float run = 0.f;
                int g = gb[0];
                bool any = false;
#pragma unroll
                for (int reg = 0; reg < 4; ++reg) {
                    int row = r0 + reg;
                    if (row >= n) break;
                    float v = fmaxf(acc[mf][nf][reg] + bcol[nf], 0.f);
                    if (gb[reg] != g) {
                        atomicAdd(pooled + (size_t)g * 512 + col, run);
                        run = 0.f;
                        g = gb[reg];
                    }
                    run += v;
                    any = true;
                }
                if (any) atomicAdd(pooled + (size_t)g * 512 + col, run);
            }
        }
    }
}

__global__ void k_logits(const float* __restrict__ pooled, const int* __restrict__ gstart,
                         const float* __restrict__ fcw, const float* __restrict__ fcb,
                         float* __restrict__ out) {
    int g = threadIdx.x;
    int cnt = gstart[g + 1] - gstart[g];
    float inv = 1.f / (float)(cnt > 1 ? cnt : 1);
    float lg[4];
#pragma unroll
    for (int o = 0; o < 4; ++o) lg[o] = fcb[o];
    for (int f = 0; f < 512; ++f) {
        float p = pooled[g * 512 + f] * inv;
#pragma unroll
        for (int o = 0; o < 4; ++o) lg[o] = fmaf(p, fcw[f * 4 + o], lg[o]);
    }
    float m = fmaxf(fmaxf(lg[0], lg[1]), fmaxf(lg[2], lg[3]));
    float s = 0.f;
#pragma unroll
    for (int o = 0; o < 4; ++o) s += expf(lg[o] - m);
    float l = logf(s);
#pragma unroll
    for (int o = 0; o < 4; ++o) out[g * 4 + o] = lg[o] - m - l;
}

// -------------------- launch --------------------

extern "C" void kernel_launch(void* const* d_in, const int* in_sizes, int n_in,
                              void* d_out, int out_size, void* d_ws, size_t ws_size,
                              hipStream_t stream) {
    const float* x   = (const float*)d_in[0];
    const int* ei    = (const int*)d_in[1];
    const int* batch = (const int*)d_in[2];
    const float* W11 = (const float*)d_in[3];
    const float* b11 = (const float*)d_in[4];
    const float* W12 = (const float*)d_in[5];
    const float* b12 = (const float*)d_in[6];
    const float* W21 = (const float*)d_in[7];
    const float* b21 = (const float*)d_in[8];
    const float* W22 = (const float*)d_in[9];
    const float* b22 = (const float*)d_in[10];
    const float* fcw = (const float*)d_in[11];
    const float* fcb = (const float*)d_in[12];
    float* out = (float*)d_out;

    const int N = in_sizes[0] / F1;
    const int E = in_sizes[1] / 2;
    const int* src = ei;
    const int* dst = ei + E;

    char* w = (char*)d_ws;
    size_t pos = 0;
    auto alloc = [&](size_t bytes) -> void* {
        void* p = w + pos;
        pos += (bytes + 255) & ~(size_t)255;
        return p;
    };
    int* cur_f   = (int*)alloc((size_t)N * 4);
    int* cur_r   = (int*)alloc((size_t)N * 4);
    int* off_f   = (int*)alloc((size_t)(N + 1) * 4);
    int* off_r   = (int*)alloc((size_t)(N + 1) * 4);
    float* dinvF = (float*)alloc((size_t)N * 4);
    float* dinvR = (float*)alloc((size_t)N * 4);
    int* nbr_f   = (int*)alloc((size_t)E * 4);
    float* w_f   = (float*)alloc((size_t)E * 4);
    int* nbr_r   = (int*)alloc((size_t)E * 4);
    float* w_r   = (float*)alloc((size_t)E * 4);
    int* blks_f  = (int*)alloc(1024);
    int* blks_r  = (int*)alloc(1024);
    int* gstart  = (int*)alloc((NGRAPH + 1) * 4);
    float* pooled = (float*)alloc((size_t)NGRAPH * 512 * 4);
    ushort_t* BpF = (ushort_t*)alloc((size_t)FT2 * O2 * 2);      // 320 KB packed W21
    ushort_t* BpR = (ushort_t*)alloc((size_t)FT2 * O2 * 2);      // 320 KB packed W22
    float* TxAll1 = (float*)alloc((size_t)N * FT1 * 4);          // 32 MB fp32
    ushort_t* TxAll2 = (ushort_t*)alloc((size_t)(N + 64) * FT2 * 2);  // 128 MB bf16 + pad
    // total ~173.4 MB

    (void)hipMemsetAsync(cur_f, 0, (size_t)N * 4, stream);
    (void)hipMemsetAsync(cur_r, 0, (size_t)N * 4, stream);
    (void)hipMemsetAsync(pooled, 0, (size_t)NGRAPH * 512 * 4, stream);

    int gE = (E + 255) / 256, gN = (N + 255) / 256;
    k_count<<<gE, 256, 0, stream>>>(src, dst, cur_f, cur_r, E);
    k_dinv<<<gN, 256, 0, stream>>>(cur_f, cur_r, dinvF, dinvR, N);

    int NB = (N + 511) / 512;
    k_scan1<<<NB, 256, 0, stream>>>(cur_f, off_f, blks_f, N);
    k_scan1<<<NB, 256, 0, stream>>>(cur_r, off_r, blks_r, N);
    k_scan2<<<1, 256, 0, stream>>>(blks_f, NB);
    k_scan2<<<1, 256, 0, stream>>>(blks_r, NB);
    k_scan3<<<NB, 256, 0, stream>>>(off_f, blks_f, N);
    k_scan3<<<NB, 256, 0, stream>>>(off_r, blks_r, N);
    k_tail<<<1, 64, 0, stream>>>(off_f, off_r, N, E);
    (void)hipMemcpyAsync(cur_f, off_f, (size_t)N * 4, hipMemcpyDeviceToDevice, stream);
    (void)hipMemcpyAsync(cur_r, off_r, (size_t)N * 4, hipMemcpyDeviceToDevice, stream);
    k_scatter<<<gE, 256, 0, stream>>>(src, dst, dinvF, dinvR, cur_f, cur_r,
                                      nbr_f, w_f, nbr_r, w_r, E);
    k_gstart<<<5, 64, 0, stream>>>(batch, gstart, N);
    k_packW<<<80, 256, 0, stream>>>(W21, BpF);
    k_packW<<<80, 256, 0, stream>>>(W22, BpR);

    // ---------------- layer 1 (fp32 Tx, F=16) ----------------
    k_copyx<<<(N * 4 + 255) / 256, 256, 0, stream>>>(x, TxAll1, N);
    int gs1 = (N * 4 + 255) / 256;
    auto C1 = [&](int k) { return TxAll1 + k * F1; };
    // fwd
    k_spmm_f32<<<gs1, 256, 0, stream>>>(C1(0), C1(1), nullptr, off_f, nbr_f, w_f, N);
    k_spmm_f32<<<gs1, 256, 0, stream>>>(C1(1), C1(2), C1(0), off_f, nbr_f, w_f, N);
    k_spmm_f32<<<gs1, 256, 0, stream>>>(C1(2), C1(3), C1(1), off_f, nbr_f, w_f, N);
    k_spmm_f32<<<gs1, 256, 0, stream>>>(C1(3), C1(4), C1(2), off_f, nbr_f, w_f, N);
    k_gemm1<<<(N + 127) / 128, 256, 0, stream>>>(TxAll1, W11, b11, TxAll2, N);
    // rev (overwrites C1(1..4); C1(0)=x preserved)
    k_spmm_f32<<<gs1, 256, 0, stream>>>(C1(0), C1(1), nullptr, off_r, nbr_r, w_r, N);
    k_spmm_f32<<<gs1, 256, 0, stream>>>(C1(1), C1(2), C1(0), off_r, nbr_r, w_r, N);
    k_spmm_f32<<<gs1, 256, 0, stream>>>(C1(2), C1(3), C1(1), off_r, nbr_r, w_r, N);
    k_spmm_f32<<<gs1, 256, 0, stream>>>(C1(3), C1(4), C1(2), off_r, nbr_r, w_r, N);
    k_gemm1<<<(N + 127) / 128, 256, 0, stream>>>(TxAll1, W12, b12, TxAll2 + O1, N);

    // ---------------- layer 2 (bf16 Tx, F=128) ----------------
    int gs2 = (N * 16 + 255) / 256;
    auto C2 = [&](int k) { return TxAll2 + k * F2; };
    int gg = (N + 63) / 64;
    // fwd
    k_spmm_bf<<<gs2, 256, 0, stream>>>(C2(0), C2(1), nullptr, off_f, nbr_f, w_f, N);
    k_spmm_bf<<<gs2, 256, 0, stream>>>(C2(1), C2(2), C2(0), off_f, nbr_f, w_f, N);
    k_spmm_bf<<<gs2, 256, 0, stream>>>(C2(2), C2(3), C2(1), off_f, nbr_f, w_f, N);
    k_spmm_bf<<<gs2, 256, 0, stream>>>(C2(3), C2(4), C2(2), off_f, nbr_f, w_f, N);
    k_gemm2_mfma<<<gg, 256, 0, stream>>>(TxAll2, BpF, b21, pooled, 0, batch, N);
    // rev
    k_spmm_bf<<<gs2, 256, 0, stream>>>(C2(0), C2(1), nullptr, off_r, nbr_r, w_r, N);
    k_spmm_bf<<<gs2, 256, 0, stream>>>(C2(1), C2(2), C2(0), off_r, nbr_r, w_r, N);
    k_spmm_bf<<<gs2, 256, 0, stream>>>(C2(2), C2(3), C2(1), off_r, nbr_r, w_r, N);
    k_spmm_bf<<<gs2, 256, 0, stream>>>(C2(3), C2(4), C2(2), off_r, nbr_r, w_r, N);
    k_gemm2_mfma<<<gg, 256, 0, stream>>>(TxAll2, BpR, b22, pooled, 256, batch, N);

    k_logits<<<1, 256, 0, stream>>>(pooled, gstart, fcw, fcb, out);
}